// Round 3
// baseline (105.318 us; speedup 1.0000x reference)
//
#include <hip/hip_runtime.h>

#define SDIM 4096
#define DDIM 64
#define HN   16
#define BH   64
#define NC   8

// ---------------------------------------------------------------------------
// k1: per (bh, chunk) compute partial KV[64][64] = sum_s K[s][d]*V[s][e]
//     (K gets relu + mask) and partial ksum[64].  (unchanged from round 2)
// ---------------------------------------------------------------------------
__global__ __launch_bounds__(256) void k1_kv(
    const float* __restrict__ K, const float* __restrict__ V,
    const int* __restrict__ mask,
    float* __restrict__ KVp, float* __restrict__ ksump)
{
    __shared__ float lds[16384];           // 64 KB: Ks[128][64] | Vs[128][64]
    float* Ks = lds;
    float* Vs = lds + 8192;

    const int bh = blockIdx.x / NC;
    const int ch = blockIdx.x % NC;
    const int b  = bh / HN;
    const int tid  = threadIdx.x;
    const int wave = tid >> 6;
    const int lane = tid & 63;
    const int di = lane >> 3;              // 0..7 (d sub-block)
    const int ej = lane & 7;               // 0..7 (e sub-block)
    const long base = (long)bh * SDIM * DDIM;
    const int s0 = ch * (SDIM / NC);       // 512 rows per block

    float acc[8][8];
#pragma unroll
    for (int i = 0; i < 8; ++i)
#pragma unroll
        for (int j = 0; j < 8; ++j) acc[i][j] = 0.f;
    float ksacc[8];
#pragma unroll
    for (int i = 0; i < 8; ++i) ksacc[i] = 0.f;

    for (int it = 0; it < (SDIM / NC) / 128; ++it) {   // 4 iters of 128 rows
        const int r0 = s0 + it * 128;
        __syncthreads();
#pragma unroll
        for (int i = 0; i < 8; ++i) {
            const int f  = tid + i * 256;      // float4 index 0..2047
            const int r  = f >> 4;             // row 0..127
            const int c4 = (f & 15) << 2;      // col 0..60
            const int sg = r0 + r;
            float4 kq = *(const float4*)(K + base + (long)sg * DDIM + c4);
            const float mv = mask[b * SDIM + sg] ? 1.f : 0.f;
            kq.x = fmaxf(kq.x, 0.f) * mv;
            kq.y = fmaxf(kq.y, 0.f) * mv;
            kq.z = fmaxf(kq.z, 0.f) * mv;
            kq.w = fmaxf(kq.w, 0.f) * mv;
            *(float4*)(Ks + r * 64 + c4) = kq;
            *(float4*)(Vs + r * 64 + c4) =
                *(const float4*)(V + base + (long)sg * DDIM + c4);
        }
        __syncthreads();
        const int rb = wave * 32;              // each wave owns 32 rows
#pragma unroll 2
        for (int s = 0; s < 32; ++s) {
            float kf[8], vf[8];
            *(float4*)(kf)     = *(const float4*)(Ks + (rb + s) * 64 + di * 8);
            *(float4*)(kf + 4) = *(const float4*)(Ks + (rb + s) * 64 + di * 8 + 4);
            *(float4*)(vf)     = *(const float4*)(Vs + (rb + s) * 64 + ej * 8);
            *(float4*)(vf + 4) = *(const float4*)(Vs + (rb + s) * 64 + ej * 8 + 4);
#pragma unroll
            for (int i = 0; i < 8; ++i)
#pragma unroll
                for (int j = 0; j < 8; ++j)
                    acc[i][j] = fmaf(kf[i], vf[j], acc[i][j]);
            if (ej == 0) {
#pragma unroll
                for (int i = 0; i < 8; ++i) ksacc[i] += kf[i];
            }
        }
    }
    __syncthreads();
#pragma unroll
    for (int i = 0; i < 8; ++i)
#pragma unroll
        for (int j = 0; j < 8; ++j)
            lds[wave * 4096 + (di * 8 + i) * 64 + ej * 8 + j] = acc[i][j];
    __syncthreads();
    float* outp = KVp + ((long)bh * NC + ch) * 4096;
    for (int i = 0; i < 16; ++i) {
        const int idx = i * 256 + tid;
        outp[idx] = lds[idx] + lds[4096 + idx] + lds[8192 + idx] + lds[12288 + idx];
    }
    __syncthreads();
    if (ej == 0) {
#pragma unroll
        for (int i = 0; i < 8; ++i) lds[wave * 64 + di * 8 + i] = ksacc[i];
    }
    __syncthreads();
    if (tid < 64) {
        ksump[((long)bh * NC + ch) * 64 + tid] =
            lds[tid] + lds[64 + tid] + lds[128 + tid] + lds[192 + tid];
    }
}

// ---------------------------------------------------------------------------
// k2: reduce NC chunk partials (in d_out scratch) -> final KV, ksum (in d_ws)
// ---------------------------------------------------------------------------
__global__ __launch_bounds__(256) void k2_reduce(
    const float* __restrict__ KVp, const float* __restrict__ ksump,
    float* __restrict__ KV, float* __restrict__ ksum)
{
    const int bh = blockIdx.x;
    const int tid = threadIdx.x;
#pragma unroll
    for (int i = 0; i < 16; ++i) {
        const int idx = i * 256 + tid;
        float v = 0.f;
#pragma unroll
        for (int c = 0; c < NC; ++c) v += KVp[((long)bh * NC + c) * 4096 + idx];
        KV[(long)bh * 4096 + idx] = v;
    }
    if (tid < 64) {
        float v = 0.f;
#pragma unroll
        for (int c = 0; c < NC; ++c) v += ksump[((long)bh * NC + c) * 64 + tid];
        ksum[bh * 64 + tid] = v;
    }
}

// ---------------------------------------------------------------------------
// k3 v2: lane e holds KV[:,e] in 64 VGPRs. Per wave: 32 rows (2 chunks of 16)
//   staged relu'd in an 8 KB wave-private LDS strip (no barriers). Numerator
//   via wave-uniform broadcast ds_read_b128 of q + per-lane FMA into one acc
//   per row (4 rows interleaved for ILP). Norm via lane-parallel q*ksum[lane]
//   + shfl_xor reduce. 256 thr, 32 KB LDS -> ~16 waves/CU.
// ---------------------------------------------------------------------------
__global__ __launch_bounds__(256, 4) void k3_out(
    const float* __restrict__ Q, const float* __restrict__ KVm,
    const float* __restrict__ ksum, float* __restrict__ out)
{
    __shared__ float qs[4][2048];          // 32 KB: per-wave 2 chunks x 16x64
    const int tid  = threadIdx.x;
    const int w    = tid >> 6;
    const int lane = tid & 63;
    const int bh    = blockIdx.x >> 5;
    const int strip = blockIdx.x & 31;     // 32 strips x 128 rows
    const int row0  = strip * 128 + w * 32;

    // KV column e=lane into registers (coalesced b32 column loads, L2-hot)
    float kv[64];
    const float* kvp = KVm + (long)bh * 4096;
#pragma unroll
    for (int d = 0; d < 64; ++d) kv[d] = kvp[d * 64 + lane];
    const float ksv = ksum[bh * 64 + lane];     // lane d holds ksum[d]

    const float* qbase = Q + ((long)bh * SDIM + row0) * DDIM;
    float*       obase = out + ((long)bh * SDIM + row0) * DDIM;

    // Stage both 16-row chunks: coalesced float4 loads, relu once, b128 LDS
    // writes (wave-private region -> no __syncthreads needed).
    float4 A[8];
#pragma unroll
    for (int i = 0; i < 8; ++i)
        A[i] = *(const float4*)(qbase + i * 256 + lane * 4);
#pragma unroll
    for (int i = 0; i < 8; ++i) {
        A[i].x = fmaxf(A[i].x, 0.f); A[i].y = fmaxf(A[i].y, 0.f);
        A[i].z = fmaxf(A[i].z, 0.f); A[i].w = fmaxf(A[i].w, 0.f);
        *(float4*)(&qs[w][i * 256 + lane * 4]) = A[i];
    }

#pragma unroll
    for (int c = 0; c < 2; ++c) {
        const float* qc = &qs[w][c * 1024];
#pragma unroll
        for (int sg = 0; sg < 4; ++sg) {
            float r0 = 0.f, r1 = 0.f, r2 = 0.f, r3 = 0.f;
#pragma unroll
            for (int dq = 0; dq < 16; ++dq) {
                // wave-uniform addresses -> LDS broadcast, conflict-free
                float4 qa = *(const float4*)(qc + (sg * 4 + 0) * 64 + dq * 4);
                float4 qb = *(const float4*)(qc + (sg * 4 + 1) * 64 + dq * 4);
                float4 qd = *(const float4*)(qc + (sg * 4 + 2) * 64 + dq * 4);
                float4 qe = *(const float4*)(qc + (sg * 4 + 3) * 64 + dq * 4);
                const float k0 = kv[dq * 4 + 0], k1 = kv[dq * 4 + 1];
                const float k2 = kv[dq * 4 + 2], k3 = kv[dq * 4 + 3];
                r0 = fmaf(qa.x, k0, r0); r0 = fmaf(qa.y, k1, r0);
                r0 = fmaf(qa.z, k2, r0); r0 = fmaf(qa.w, k3, r0);
                r1 = fmaf(qb.x, k0, r1); r1 = fmaf(qb.y, k1, r1);
                r1 = fmaf(qb.z, k2, r1); r1 = fmaf(qb.w, k3, r1);
                r2 = fmaf(qd.x, k0, r2); r2 = fmaf(qd.y, k1, r2);
                r2 = fmaf(qd.z, k2, r2); r2 = fmaf(qd.w, k3, r2);
                r3 = fmaf(qe.x, k0, r3); r3 = fmaf(qe.y, k1, r3);
                r3 = fmaf(qe.z, k2, r3); r3 = fmaf(qe.w, k3, r3);
            }
            // norms for these 4 rows: lane-parallel partial + shfl reduce
            float res[4] = {r0, r1, r2, r3};
#pragma unroll
            for (int i = 0; i < 4; ++i) {
                const int s = sg * 4 + i;
                float p = qc[s * 64 + lane] * ksv;   // coalesced b32, lane=d
#pragma unroll
                for (int off = 32; off >= 1; off >>= 1)
                    p += __shfl_xor(p, off);
                const float inv = 1.0f / p;
                obase[(c * 16 + s) * 64 + lane] = res[i] * inv;
            }
        }
    }
}

extern "C" void kernel_launch(void* const* d_in, const int* in_sizes, int n_in,
                              void* d_out, int out_size, void* d_ws, size_t ws_size,
                              hipStream_t stream)
{
    const float* Q    = (const float*)d_in[0];
    const float* K    = (const float*)d_in[1];
    const float* V    = (const float*)d_in[2];
    const int*   mask = (const int*)d_in[3];
    float* out = (float*)d_out;

    // Chunk partials live in d_out (scratch; k3 overwrites all of d_out).
    float* KVp   = out;                                // 8.4 MB scratch
    float* ksump = KVp + (long)BH * NC * 4096;         // 128 KB
    float* KV    = (float*)d_ws;                       // 1 MB
    float* ksum  = KV + (long)BH * 4096;               // 16 KB

    hipLaunchKernelGGL(k1_kv, dim3(BH * NC), dim3(256), 0, stream,
                       K, V, mask, KVp, ksump);
    hipLaunchKernelGGL(k2_reduce, dim3(BH), dim3(256), 0, stream,
                       KVp, ksump, KV, ksum);
    hipLaunchKernelGGL(k3_out, dim3(BH * 32), dim3(256), 0, stream,
                       Q, KV, ksum, out);
}